// Round 7
// baseline (122.717 us; speedup 1.0000x reference)
//
#include <hip/hip_runtime.h>
#include <hip/hip_bf16.h>
#include <stdint.h>

// ---------------------------------------------------------------------------
// Head: out = softmax((x Wq)(x Wk)^T / 8) (x Wv)
// B=8, T=2048, C=512, D=64.  ALL I/O FP32; internals bf16 MFMA + fp32 accum.
//
// R7: reuse-sharing. R6 (frag-order layouts) fixed per-load segmentation;
// remaining costs are redundant re-reads:
//   proj: block = ONE matrix x 4 token tiles -> 4 waves load IDENTICAL W
//         addresses in near-lockstep (L1 serves 3 of 4).
//   attn: block = 32 q-rows, waves = 2 q-tiles x 2 key-halves; total KV
//         traffic from L2 halves (512->256 MB); twin waves share addresses.
//         Epilogue combines key-half partials (no-max softmax: plain sums).
// Keep: frag-order kg2/vg2/xb2/wt2, no-max softmax, XCD batch swizzle,
//       launch_bounds(256,1) (R3: min-waves=4 caused 96MB scratch spill).
//
// MFMA 16x16x32 bf16 fragment maps (gfx950, m89/m91-verified):
//   A: lane holds A[m=lane&15][k=quad*8+j]   (quad=lane>>4, j=0..7)
//   B: lane holds B[k=quad*8+j][n=lane&15]
//   D: lane holds D[row=quad*4+r][col=lane&15] (r=reg 0..3)
//
// Fragment-order chunk layouts (16B chunks, chunk's 8 elems = j=0..7):
//   xb2: chunk[((tt*16+ks)*4+quad)*16+c] = x[tt*16+c][ks*32+quad*8+j]
//   wt2: chunk[(((w*4+mt)*16+ks)*4+quad)*16+c] = W_w[ks*32+quad*8+j][mt*16+c]
//   kg2: chunk[b*16384 + ((g*2+h)*4+quad)*16+c] = K[b][g*16+c][h*32+quad*8+j]
//   vg2: chunk[b*16384 + ((s*4+mt)*4+quad)*16+c] = V[b][s*32+quad*8+j][mt*16+c]
// ---------------------------------------------------------------------------

typedef short bf16x8 __attribute__((ext_vector_type(8)));
typedef float f32x4 __attribute__((ext_vector_type(4)));

#define MFMA_BF16 __builtin_amdgcn_mfma_f32_16x16x32_bf16

__device__ __forceinline__ unsigned int pk2(float a, float b) {
    __hip_bfloat162 h = __float22bfloat162_rn(float2{a, b});   // v_cvt_pk_bf16_f32
    union { __hip_bfloat162 h; unsigned int u; } r; r.h = h;
    return r.u;
}

__device__ __forceinline__ uint2 pack4_bf16(float a, float b, float c, float d) {
    uint2 r; r.x = pk2(a, b); r.y = pk2(c, d); return r;
}

__device__ __forceinline__ bf16x8 cvt8(f32x4 a, f32x4 b) {
    union { bf16x8 v; unsigned int u[4]; } r;
    r.u[0] = pk2(a[0], a[1]); r.u[1] = pk2(a[2], a[3]);
    r.u[2] = pk2(b[0], b[1]); r.u[3] = pk2(b[2], b[3]);
    return r.v;
}

__device__ __forceinline__ unsigned short bf1(float a) {
    __hip_bfloat16 h = __float2bfloat16(a);
    union { __hip_bfloat16 h; unsigned short u; } r; r.h = h;
    return r.u;
}

// ---------------------------------------------------------------------------
// Kernel 0: W fp32 -> wt2 bf16 fragment-order chunks. 12288 threads.
// ---------------------------------------------------------------------------
__global__ void wt_kernel(const float* __restrict__ Wq,
                          const float* __restrict__ Wk,
                          const float* __restrict__ Wv,
                          unsigned short* __restrict__ wt2)
{
    int id = blockIdx.x * 256 + threadIdx.x;      // 12288 = 3*4*16*4*16
    int c    = id & 15;
    int quad = (id >> 4) & 3;
    int ks   = (id >> 6) & 15;
    int mt   = (id >> 10) & 3;
    int w    = id >> 12;
    const float* src = (w == 0) ? Wq : ((w == 1) ? Wk : Wv);
    const int n  = mt * 16 + c;
    const int k0 = ks * 32 + quad * 8;
    unsigned short* dst = wt2 + (size_t)id * 8;
    #pragma unroll
    for (int j = 0; j < 8; j++)
        dst[j] = bf1(src[(size_t)(k0 + j) * 64 + n]);
}

// ---------------------------------------------------------------------------
// Kernel 0b: x fp32 -> xb2 bf16 fragment-order chunks.
// ---------------------------------------------------------------------------
__global__ void xconv_kernel(const float* __restrict__ x,
                             unsigned short* __restrict__ xb2)
{
    int i = blockIdx.x * 256 + threadIdx.x;       // i = tok*64 + dblock
    int tok    = i >> 6;
    int dblock = i & 63;                          // d0 = dblock*8
    f32x4 a = *(const f32x4*)(x + (size_t)i * 8);
    f32x4 b = *(const f32x4*)(x + (size_t)i * 8 + 4);
    int tt = tok >> 4, c = tok & 15;
    int ks = dblock >> 2, quad = dblock & 3;
    size_t chunk = ((size_t)(tt * 16 + ks) * 4 + quad) * 16 + c;
    *(bf16x8*)(xb2 + chunk * 8) = cvt8(a, b);
}

// ---------------------------------------------------------------------------
// Kernel 1: projections. Block = ONE matrix x 4 token tiles -> the 4 waves
// issue IDENTICAL W-frag addresses (L1-shared); x frags distinct (1KB each).
// 768 blocks x 4 waves.
// ---------------------------------------------------------------------------
__global__ __launch_bounds__(256, 1) void proj_kernel(
    const unsigned short* __restrict__ xb2, const unsigned short* __restrict__ wt2,
    unsigned short* __restrict__ qg, unsigned short* __restrict__ kg2,
    unsigned short* __restrict__ vg2)
{
    const int lane = threadIdx.x & 63;
    const int c    = lane & 15;
    const int quad = lane >> 4;
    const int wave = threadIdx.x >> 6;
    const int w    = blockIdx.x % 3;              // matrix: 0:q 1:k 2:v
    const int tt   = (blockIdx.x / 3) * 4 + wave; // token tile 0..1023
    const int t0   = tt * 16;

    f32x4 acc[4];
    #pragma unroll
    for (int i = 0; i < 4; i++) acc[i] = f32x4{0.f, 0.f, 0.f, 0.f};

    const unsigned short* xbase = xb2 + ((size_t)tt * 16 * 64 + lane) * 8;
    const unsigned short* wbase = wt2 + ((size_t)w * 4 * 16 * 64 + lane) * 8;

    #pragma unroll 4
    for (int ks = 0; ks < 16; ks++) {
        bf16x8 xf = *(const bf16x8*)(xbase + (size_t)ks * 64 * 8);
        #pragma unroll
        for (int mt = 0; mt < 4; mt++) {
            bf16x8 wa = *(const bf16x8*)(wbase + ((size_t)mt * 16 + ks) * 64 * 8);
            acc[mt] = MFMA_BF16(wa, xf, acc[mt], 0, 0, 0);
        }
    }

    const int b  = t0 >> 11;             // batch
    const int tb = t0 & 2047;            // batch-local tile base

    if (w == 0) {
        unsigned short* base = qg + (size_t)(t0 + c) * 64;
        #pragma unroll
        for (int mt = 0; mt < 4; mt++)
            *(uint2*)(base + mt * 16 + quad * 4) =
                pack4_bf16(acc[mt][0], acc[mt][1], acc[mt][2], acc[mt][3]);
    } else if (w == 1) {
        const int g = tb >> 4;
        #pragma unroll
        for (int mt = 0; mt < 4; mt++) {
            const int h  = mt >> 1;
            const int qk = (mt & 1) * 2 + (quad >> 1);
            size_t chunk = (size_t)b * 16384 + ((size_t)(g * 2 + h) * 4 + qk) * 16 + c;
            *(uint2*)(kg2 + chunk * 8 + (quad & 1) * 4) =
                pack4_bf16(acc[mt][0], acc[mt][1], acc[mt][2], acc[mt][3]);
        }
    } else {
        const int tk = tb + c;
        const int s  = tk >> 5;
        const int qv = (tk >> 3) & 3;
        const int j  = tk & 7;
        #pragma unroll
        for (int mt = 0; mt < 4; mt++) {
            size_t chunk = (size_t)b * 16384 + ((size_t)(s * 4 + mt) * 4 + qv) * 16 + quad * 4;
            unsigned short* dst = vg2 + chunk * 8 + j;
            dst[0]  = bf1(acc[mt][0]);
            dst[8]  = bf1(acc[mt][1]);
            dst[16] = bf1(acc[mt][2]);
            dst[24] = bf1(acc[mt][3]);
        }
    }
}

// ---------------------------------------------------------------------------
// Kernel 2: flash attention. Block = 32 q-rows; wave = (q-tile qi, key-half h).
// Twin waves (same h) read identical K/V addresses -> L1 hits; total KV from
// L2 halves vs R6. 512 blocks x 4 waves. Epilogue: add the two key-half
// partials per q-tile (no-max softmax partials are plain sums).
// ---------------------------------------------------------------------------
__global__ __launch_bounds__(256, 1) void attn_kernel(
    const unsigned short* __restrict__ qg, const unsigned short* __restrict__ kg2,
    const unsigned short* __restrict__ vg2, float* __restrict__ out)
{
    __shared__ unsigned short pt[4][16 * 136];   // per-wave P [q=16][key=128]
    __shared__ float obuf[4][16][68];            // partial O [wave][q][d]
    __shared__ float lbuf[4][16];

    const int lane = threadIdx.x & 63;
    const int wave = threadIdx.x >> 6;
    const int c    = lane & 15;
    const int quad = lane >> 4;
    const int b    = blockIdx.x & 7;             // batch -> XCD (L2 locality)
    const int g    = blockIdx.x >> 3;            // 32-row group (0..63)
    const int qi   = wave & 1;                   // q-tile within block
    const int h    = wave >> 1;                  // key half (0..1)
    const int tb   = b * 2048 + g * 32;          // block q base
    const int t0   = tb + qi * 16;               // wave q-tile base

    unsigned short* ptw = &pt[wave][0];
    const unsigned short* kbase = kg2 + ((size_t)b * 16384 + lane) * 8;
    const unsigned short* vbase = vg2 + ((size_t)b * 16384 + lane) * 8;

    bf16x8 qb0 = *(const bf16x8*)(qg + (size_t)(t0 + c) * 64 + quad * 8);
    bf16x8 qb1 = *(const bf16x8*)(qg + (size_t)(t0 + c) * 64 + 32 + quad * 8);

    f32x4 o0 = {0,0,0,0}, o1 = {0,0,0,0}, o2 = {0,0,0,0}, o3 = {0,0,0,0};
    f32x4 lacc = {0,0,0,0};
    const float cexp = 0.18033688011112042f;   // log2(e)/8  (scores = raw/8)

    for (int kt = h * 8; kt < h * 8 + 8; kt++) {
        const int key0 = kt * 128;
        const int g0   = key0 >> 4;              // 16-key group base
        const int s0   = key0 >> 5;              // 32-key block base

        // ---- S^T = K·Q^T; each ka load = contiguous 1KB ----
        f32x4 st[8];
        const f32x4 z = {0,0,0,0};
        #pragma unroll
        for (int mt = 0; mt < 8; mt++) {
            bf16x8 k0 = *(const bf16x8*)(kbase + (size_t)((g0 + mt) * 2    ) * 64 * 8);
            bf16x8 k1 = *(const bf16x8*)(kbase + (size_t)((g0 + mt) * 2 + 1) * 64 * 8);
            st[mt] = MFMA_BF16(k0, qb0, z, 0, 0, 0);
            st[mt] = MFMA_BF16(k1, qb1, st[mt], 0, 0, 0);
        }

        // ---- preload V ks=0,1 so latency hides under exp section ----
        bf16x8 va[2][4];
        #pragma unroll
        for (int mt = 0; mt < 4; mt++) {
            va[0][mt] = *(const bf16x8*)(vbase + (size_t)((s0    ) * 4 + mt) * 64 * 8);
            va[1][mt] = *(const bf16x8*)(vbase + (size_t)((s0 + 1) * 4 + mt) * 64 * 8);
        }

        // ---- p = exp2(s*c) via v_exp_f32; per-lane l accumulation ----
        asm volatile("" ::: "memory");
        #pragma unroll
        for (int mt = 0; mt < 8; mt++) {
            float p0 = __builtin_amdgcn_exp2f(st[mt][0] * cexp);
            float p1 = __builtin_amdgcn_exp2f(st[mt][1] * cexp);
            float p2 = __builtin_amdgcn_exp2f(st[mt][2] * cexp);
            float p3 = __builtin_amdgcn_exp2f(st[mt][3] * cexp);
            lacc[0] += p0; lacc[1] += p1; lacc[2] += p2; lacc[3] += p3;
            // P[q=c][key = mt*16 + quad*4 + r] -> one 8B write
            *(uint2*)(ptw + c * 136 + mt * 16 + quad * 4) = pack4_bf16(p0, p1, p2, p3);
        }
        asm volatile("" ::: "memory");

        // ---- O^T += V^T·P^T; va 2-deep double buffer ----
        #pragma unroll
        for (int ks = 0; ks < 4; ks++) {
            bf16x8 pb = *(const bf16x8*)(ptw + c * 136 + ks * 32 + quad * 8);
            bf16x8 v0 = va[ks & 1][0], v1 = va[ks & 1][1];
            bf16x8 v2 = va[ks & 1][2], v3 = va[ks & 1][3];
            if (ks < 2) {
                #pragma unroll
                for (int mt = 0; mt < 4; mt++)
                    va[ks & 1][mt] =
                        *(const bf16x8*)(vbase + (size_t)((s0 + ks + 2) * 4 + mt) * 64 * 8);
            }
            o0 = MFMA_BF16(v0, pb, o0, 0, 0, 0);
            o1 = MFMA_BF16(v1, pb, o1, 0, 0, 0);
            o2 = MFMA_BF16(v2, pb, o2, 0, 0, 0);
            o3 = MFMA_BF16(v3, pb, o3, 0, 0, 0);
        }
        asm volatile("" ::: "memory");
    }

    // ---- one l reduction per wave ----
    float l = (lacc[0] + lacc[1]) + (lacc[2] + lacc[3]);
    l += __shfl_xor(l, 16);
    l += __shfl_xor(l, 32);

    // ---- publish partials: O^T D-layout row=d=mt*16+quad*4+r, col=q=c ----
    *(f32x4*)&obuf[wave][c][ 0 + quad * 4] = o0;
    *(f32x4*)&obuf[wave][c][16 + quad * 4] = o1;
    *(f32x4*)&obuf[wave][c][32 + quad * 4] = o2;
    *(f32x4*)&obuf[wave][c][48 + quad * 4] = o3;
    if (quad == 0) lbuf[wave][c] = l;
    __syncthreads();

    // ---- combine the two key-halves per q-tile; 256 thr x 8 floats ----
    const int tid = threadIdx.x;
    const int qr  = tid >> 3;                    // block-local q row (0..31)
    const int d0  = (tid & 7) * 8;               // d base (0..56)
    const int q2  = qr >> 4;                     // q-tile (wave qi)
    const int q16 = qr & 15;
    const float L = lbuf[q2][q16] + lbuf[q2 + 2][q16];
    const float rl = 1.f / L;
    f32x4 Oa, Ob;
    {
        f32x4 a0 = *(const f32x4*)&obuf[q2][q16][d0];
        f32x4 a1 = *(const f32x4*)&obuf[q2 + 2][q16][d0];
        f32x4 b0 = *(const f32x4*)&obuf[q2][q16][d0 + 4];
        f32x4 b1 = *(const f32x4*)&obuf[q2 + 2][q16][d0 + 4];
        Oa[0]=(a0[0]+a1[0])*rl; Oa[1]=(a0[1]+a1[1])*rl;
        Oa[2]=(a0[2]+a1[2])*rl; Oa[3]=(a0[3]+a1[3])*rl;
        Ob[0]=(b0[0]+b1[0])*rl; Ob[1]=(b0[1]+b1[1])*rl;
        Ob[2]=(b0[2]+b1[2])*rl; Ob[3]=(b0[3]+b1[3])*rl;
    }
    float* op = out + (size_t)(tb + qr) * 64 + d0;
    *(f32x4*)op       = Oa;
    *(f32x4*)(op + 4) = Ob;
}

// ---------------------------------------------------------------------------
extern "C" void kernel_launch(void* const* d_in, const int* in_sizes, int n_in,
                              void* d_out, int out_size, void* d_ws, size_t ws_size,
                              hipStream_t stream)
{
    const float* x  = (const float*)d_in[0];
    const float* Wk = (const float*)d_in[1];
    const float* Wq = (const float*)d_in[2];
    const float* Wv = (const float*)d_in[3];
    float* out = (float*)d_out;

    char* ws = (char*)d_ws;
    unsigned short* qg  = (unsigned short*)(ws);                  // 2 MiB
    unsigned short* kg2 = (unsigned short*)(ws + (2u << 20));     // 2 MiB
    unsigned short* vg2 = (unsigned short*)(ws + (4u << 20));     // 2 MiB
    unsigned short* wt2 = (unsigned short*)(ws + (6u << 20));     // 192 KiB
    unsigned short* xb2 = (unsigned short*)(ws + (7u << 20));     // 16 MiB

    hipLaunchKernelGGL(wt_kernel,    dim3(48),   dim3(256), 0, stream, Wq, Wk, Wv, wt2);
    hipLaunchKernelGGL(xconv_kernel, dim3(4096), dim3(256), 0, stream, x, xb2);
    hipLaunchKernelGGL(proj_kernel,  dim3(768),  dim3(256), 0, stream, xb2, wt2, qg, kg2, vg2);
    hipLaunchKernelGGL(attn_kernel,  dim3(512),  dim3(256), 0, stream, qg, kg2, vg2, out);
}

// Round 8
// 110.240 us; speedup vs baseline: 1.1132x; 1.1132x over previous
//
#include <hip/hip_runtime.h>
#include <hip/hip_bf16.h>
#include <stdint.h>

// ---------------------------------------------------------------------------
// Head: out = softmax((x Wq)(x Wk)^T / 8) (x Wv)
// B=8, T=2048, C=512, D=64.  ALL I/O FP32; internals bf16 MFMA + fp32 accum.
//
// R8: in-wave KV reuse. R7's cross-wave L1 sharing regressed (lockstep
// drift + occupancy loss, KV L2 traffic unchanged at ~512 MB). Now each
// attn wave computes TWO q-tiles (32 q-rows) over its 512-key range: K and
// V fragments loaded once serve both tiles -> KV L2 traffic halves to
// ~256 MB by construction. proj reverted to R6 exactly; wt merged into
// xconv (one launch fewer).
// Keep: frag-order layouts (R6's big win), no-max softmax, XCD batch
// swizzle, launch_bounds(256,1) (R3: min-waves=4 caused 96MB scratch spill).
//
// MFMA 16x16x32 bf16 fragment maps (gfx950, m89/m91-verified):
//   A: lane holds A[m=lane&15][k=quad*8+j]   (quad=lane>>4, j=0..7)
//   B: lane holds B[k=quad*8+j][n=lane&15]
//   D: lane holds D[row=quad*4+r][col=lane&15] (r=reg 0..3)
//
// Fragment-order chunk layouts (16B chunks, chunk's 8 elems = j=0..7):
//   xb2: chunk[((tt*16+ks)*4+quad)*16+c] = x[tt*16+c][ks*32+quad*8+j]
//   wt2: chunk[(((w*4+mt)*16+ks)*4+quad)*16+c] = W_w[ks*32+quad*8+j][mt*16+c]
//   kg2: chunk[b*16384 + ((g*2+h)*4+quad)*16+c] = K[b][g*16+c][h*32+quad*8+j]
//   vg2: chunk[b*16384 + ((s*4+mt)*4+quad)*16+c] = V[b][s*32+quad*8+j][mt*16+c]
// ---------------------------------------------------------------------------

typedef short bf16x8 __attribute__((ext_vector_type(8)));
typedef float f32x4 __attribute__((ext_vector_type(4)));

#define MFMA_BF16 __builtin_amdgcn_mfma_f32_16x16x32_bf16

__device__ __forceinline__ unsigned int pk2(float a, float b) {
    __hip_bfloat162 h = __float22bfloat162_rn(float2{a, b});   // v_cvt_pk_bf16_f32
    union { __hip_bfloat162 h; unsigned int u; } r; r.h = h;
    return r.u;
}

__device__ __forceinline__ uint2 pack4_bf16(float a, float b, float c, float d) {
    uint2 r; r.x = pk2(a, b); r.y = pk2(c, d); return r;
}

__device__ __forceinline__ bf16x8 cvt8(f32x4 a, f32x4 b) {
    union { bf16x8 v; unsigned int u[4]; } r;
    r.u[0] = pk2(a[0], a[1]); r.u[1] = pk2(a[2], a[3]);
    r.u[2] = pk2(b[0], b[1]); r.u[3] = pk2(b[2], b[3]);
    return r.v;
}

__device__ __forceinline__ unsigned short bf1(float a) {
    __hip_bfloat16 h = __float2bfloat16(a);
    union { __hip_bfloat16 h; unsigned short u; } r; r.h = h;
    return r.u;
}

// ---------------------------------------------------------------------------
// Kernel 0: prep = wt (blocks 0..47) + xconv (blocks 48..4143).
// ---------------------------------------------------------------------------
__global__ void prep_kernel(const float* __restrict__ x,
                            const float* __restrict__ Wq,
                            const float* __restrict__ Wk,
                            const float* __restrict__ Wv,
                            unsigned short* __restrict__ xb2,
                            unsigned short* __restrict__ wt2)
{
    if (blockIdx.x < 48) {
        int id = blockIdx.x * 256 + threadIdx.x;      // 12288 = 3*4*16*4*16
        int c    = id & 15;
        int quad = (id >> 4) & 3;
        int ks   = (id >> 6) & 15;
        int mt   = (id >> 10) & 3;
        int w    = id >> 12;
        const float* src = (w == 0) ? Wq : ((w == 1) ? Wk : Wv);
        const int n  = mt * 16 + c;
        const int k0 = ks * 32 + quad * 8;
        unsigned short* dst = wt2 + (size_t)id * 8;
        #pragma unroll
        for (int j = 0; j < 8; j++)
            dst[j] = bf1(src[(size_t)(k0 + j) * 64 + n]);
        return;
    }
    int i = (blockIdx.x - 48) * 256 + threadIdx.x;    // i = tok*64 + dblock
    int tok    = i >> 6;
    int dblock = i & 63;
    f32x4 a = *(const f32x4*)(x + (size_t)i * 8);
    f32x4 b = *(const f32x4*)(x + (size_t)i * 8 + 4);
    int tt = tok >> 4, c = tok & 15;
    int ks = dblock >> 2, quad = dblock & 3;
    size_t chunk = ((size_t)(tt * 16 + ks) * 4 + quad) * 16 + c;
    *(bf16x8*)(xb2 + chunk * 8) = cvt8(a, b);
}

// ---------------------------------------------------------------------------
// Kernel 1: projections (exact R6). One wave = 16 tokens x one matrix; both
// operands fragment-order -> every load is base + lane*16B (contiguous 1KB).
// 768 blocks x 4 waves = 3072 waves.
// ---------------------------------------------------------------------------
__global__ __launch_bounds__(256, 1) void proj_kernel(
    const unsigned short* __restrict__ xb2, const unsigned short* __restrict__ wt2,
    unsigned short* __restrict__ qg, unsigned short* __restrict__ kg2,
    unsigned short* __restrict__ vg2)
{
    const int lane = threadIdx.x & 63;
    const int c    = lane & 15;
    const int quad = lane >> 4;
    const int wave = threadIdx.x >> 6;
    const int gw   = blockIdx.x * 4 + wave;   // 0..3071
    const int w    = gw % 3;                  // matrix: 0:q 1:k 2:v
    const int tt   = gw / 3;                  // token tile 0..1023
    const int t0   = tt * 16;

    f32x4 acc[4];
    #pragma unroll
    for (int i = 0; i < 4; i++) acc[i] = f32x4{0.f, 0.f, 0.f, 0.f};

    const unsigned short* xbase = xb2 + ((size_t)tt * 16 * 64 + lane) * 8;
    const unsigned short* wbase = wt2 + ((size_t)w * 4 * 16 * 64 + lane) * 8;

    #pragma unroll 4
    for (int ks = 0; ks < 16; ks++) {
        bf16x8 xf = *(const bf16x8*)(xbase + (size_t)ks * 64 * 8);
        #pragma unroll
        for (int mt = 0; mt < 4; mt++) {
            bf16x8 wa = *(const bf16x8*)(wbase + ((size_t)mt * 16 + ks) * 64 * 8);
            acc[mt] = MFMA_BF16(wa, xf, acc[mt], 0, 0, 0);
        }
    }

    const int b  = t0 >> 11;             // batch
    const int tb = t0 & 2047;            // batch-local tile base

    if (w == 0) {
        unsigned short* base = qg + (size_t)(t0 + c) * 64;
        #pragma unroll
        for (int mt = 0; mt < 4; mt++)
            *(uint2*)(base + mt * 16 + quad * 4) =
                pack4_bf16(acc[mt][0], acc[mt][1], acc[mt][2], acc[mt][3]);
    } else if (w == 1) {
        const int g = tb >> 4;
        #pragma unroll
        for (int mt = 0; mt < 4; mt++) {
            const int h  = mt >> 1;
            const int qk = (mt & 1) * 2 + (quad >> 1);
            size_t chunk = (size_t)b * 16384 + ((size_t)(g * 2 + h) * 4 + qk) * 16 + c;
            *(uint2*)(kg2 + chunk * 8 + (quad & 1) * 4) =
                pack4_bf16(acc[mt][0], acc[mt][1], acc[mt][2], acc[mt][3]);
        }
    } else {
        const int tk = tb + c;
        const int s  = tk >> 5;
        const int qv = (tk >> 3) & 3;
        const int j  = tk & 7;
        #pragma unroll
        for (int mt = 0; mt < 4; mt++) {
            size_t chunk = (size_t)b * 16384 + ((size_t)(s * 4 + mt) * 4 + qv) * 16 + quad * 4;
            unsigned short* dst = vg2 + chunk * 8 + j;
            dst[0]  = bf1(acc[mt][0]);
            dst[8]  = bf1(acc[mt][1]);
            dst[16] = bf1(acc[mt][2]);
            dst[24] = bf1(acc[mt][3]);
        }
    }
}

// ---------------------------------------------------------------------------
// Kernel 2: flash attention, 2 q-tiles per wave (in-wave KV reuse).
//   Block = 32 q-rows; the 4 waves split the 2048 keys 4 ways (512 each).
//   Per 128-key tile: K frags loaded once -> S for BOTH q-tiles; V frags
//   loaded once -> PV for BOTH q-tiles. No-max softmax; l reduced once.
//   Epilogue: sum the 4 key-range partials per q-row, divide, store fp32.
// 512 blocks x 256 threads; LDS ~70 KB -> 2 blocks/CU -> 8 waves/CU.
// ---------------------------------------------------------------------------
__global__ __launch_bounds__(256, 1) void attn_kernel(
    const unsigned short* __restrict__ qg, const unsigned short* __restrict__ kg2,
    const unsigned short* __restrict__ vg2, float* __restrict__ out)
{
    __shared__ unsigned short pt[4][2][16 * 136];  // [wave][qtile][q][key]
    __shared__ float obuf[4][2][16][68];           // [wave][qtile][q][d]
    __shared__ float lbuf[4][2][16];

    const int lane = threadIdx.x & 63;
    const int wave = threadIdx.x >> 6;
    const int c    = lane & 15;
    const int quad = lane >> 4;
    const int b    = blockIdx.x & 7;             // batch -> XCD (L2 locality)
    const int g    = blockIdx.x >> 3;            // 32-row group (0..63)
    const int tb   = b * 2048 + g * 32;          // block q base

    unsigned short* ptw = &pt[wave][0][0];
    const unsigned short* kbase = kg2 + ((size_t)b * 16384 + lane) * 8;
    const unsigned short* vbase = vg2 + ((size_t)b * 16384 + lane) * 8;

    // Q frags for both q-tiles
    bf16x8 qa0 = *(const bf16x8*)(qg + (size_t)(tb + c) * 64 + quad * 8);
    bf16x8 qa1 = *(const bf16x8*)(qg + (size_t)(tb + c) * 64 + 32 + quad * 8);
    bf16x8 qc0 = *(const bf16x8*)(qg + (size_t)(tb + 16 + c) * 64 + quad * 8);
    bf16x8 qc1 = *(const bf16x8*)(qg + (size_t)(tb + 16 + c) * 64 + 32 + quad * 8);

    f32x4 oa0 = {0,0,0,0}, oa1 = {0,0,0,0}, oa2 = {0,0,0,0}, oa3 = {0,0,0,0};
    f32x4 ob0 = {0,0,0,0}, ob1 = {0,0,0,0}, ob2 = {0,0,0,0}, ob3 = {0,0,0,0};
    f32x4 laccA = {0,0,0,0}, laccB = {0,0,0,0};
    const float cexp = 0.18033688011112042f;   // log2(e)/8  (scores = raw/8)

    for (int kt = wave * 4; kt < wave * 4 + 4; kt++) {
        const int key0 = kt * 128;
        const int g0   = key0 >> 4;              // 16-key group base
        const int s0   = key0 >> 5;              // 32-key block base

        // ---- S^T = K·Q^T for BOTH q-tiles; K frags loaded once ----
        f32x4 stA[8], stB[8];
        const f32x4 z = {0,0,0,0};
        #pragma unroll
        for (int mt = 0; mt < 8; mt++) {
            bf16x8 k0 = *(const bf16x8*)(kbase + (size_t)((g0 + mt) * 2    ) * 64 * 8);
            bf16x8 k1 = *(const bf16x8*)(kbase + (size_t)((g0 + mt) * 2 + 1) * 64 * 8);
            stA[mt] = MFMA_BF16(k0, qa0, z, 0, 0, 0);
            stA[mt] = MFMA_BF16(k1, qa1, stA[mt], 0, 0, 0);
            stB[mt] = MFMA_BF16(k0, qc0, z, 0, 0, 0);
            stB[mt] = MFMA_BF16(k1, qc1, stB[mt], 0, 0, 0);
        }

        // ---- preload V ks=0,1 so latency hides under exp section ----
        bf16x8 va[2][4];
        #pragma unroll
        for (int mt = 0; mt < 4; mt++) {
            va[0][mt] = *(const bf16x8*)(vbase + (size_t)((s0    ) * 4 + mt) * 64 * 8);
            va[1][mt] = *(const bf16x8*)(vbase + (size_t)((s0 + 1) * 4 + mt) * 64 * 8);
        }

        // ---- p = exp2(s*c); per-lane l accumulation; P -> LDS ----
        asm volatile("" ::: "memory");
        #pragma unroll
        for (int mt = 0; mt < 8; mt++) {
            float p0 = __builtin_amdgcn_exp2f(stA[mt][0] * cexp);
            float p1 = __builtin_amdgcn_exp2f(stA[mt][1] * cexp);
            float p2 = __builtin_amdgcn_exp2f(stA[mt][2] * cexp);
            float p3 = __builtin_amdgcn_exp2f(stA[mt][3] * cexp);
            laccA[0] += p0; laccA[1] += p1; laccA[2] += p2; laccA[3] += p3;
            *(uint2*)(ptw + c * 136 + mt * 16 + quad * 4) = pack4_bf16(p0, p1, p2, p3);
        }
        #pragma unroll
        for (int mt = 0; mt < 8; mt++) {
            float p0 = __builtin_amdgcn_exp2f(stB[mt][0] * cexp);
            float p1 = __builtin_amdgcn_exp2f(stB[mt][1] * cexp);
            float p2 = __builtin_amdgcn_exp2f(stB[mt][2] * cexp);
            float p3 = __builtin_amdgcn_exp2f(stB[mt][3] * cexp);
            laccB[0] += p0; laccB[1] += p1; laccB[2] += p2; laccB[3] += p3;
            *(uint2*)(ptw + 2176 + c * 136 + mt * 16 + quad * 4) = pack4_bf16(p0, p1, p2, p3);
        }
        asm volatile("" ::: "memory");

        // ---- O^T += V^T·P^T for BOTH q-tiles; V frags loaded once ----
        #pragma unroll
        for (int ks = 0; ks < 4; ks++) {
            bf16x8 pbA = *(const bf16x8*)(ptw + c * 136 + ks * 32 + quad * 8);
            bf16x8 pbB = *(const bf16x8*)(ptw + 2176 + c * 136 + ks * 32 + quad * 8);
            bf16x8 v0 = va[ks & 1][0], v1 = va[ks & 1][1];
            bf16x8 v2 = va[ks & 1][2], v3 = va[ks & 1][3];
            if (ks < 2) {
                #pragma unroll
                for (int mt = 0; mt < 4; mt++)
                    va[ks & 1][mt] =
                        *(const bf16x8*)(vbase + (size_t)((s0 + ks + 2) * 4 + mt) * 64 * 8);
            }
            oa0 = MFMA_BF16(v0, pbA, oa0, 0, 0, 0);
            oa1 = MFMA_BF16(v1, pbA, oa1, 0, 0, 0);
            oa2 = MFMA_BF16(v2, pbA, oa2, 0, 0, 0);
            oa3 = MFMA_BF16(v3, pbA, oa3, 0, 0, 0);
            ob0 = MFMA_BF16(v0, pbB, ob0, 0, 0, 0);
            ob1 = MFMA_BF16(v1, pbB, ob1, 0, 0, 0);
            ob2 = MFMA_BF16(v2, pbB, ob2, 0, 0, 0);
            ob3 = MFMA_BF16(v3, pbB, ob3, 0, 0, 0);
        }
        asm volatile("" ::: "memory");
    }

    // ---- one l reduction per wave per q-tile ----
    float lA = (laccA[0] + laccA[1]) + (laccA[2] + laccA[3]);
    lA += __shfl_xor(lA, 16);
    lA += __shfl_xor(lA, 32);
    float lB = (laccB[0] + laccB[1]) + (laccB[2] + laccB[3]);
    lB += __shfl_xor(lB, 16);
    lB += __shfl_xor(lB, 32);

    // ---- publish partials: O^T D-layout row=d=mt*16+quad*4+r, col=q=c ----
    *(f32x4*)&obuf[wave][0][c][ 0 + quad * 4] = oa0;
    *(f32x4*)&obuf[wave][0][c][16 + quad * 4] = oa1;
    *(f32x4*)&obuf[wave][0][c][32 + quad * 4] = oa2;
    *(f32x4*)&obuf[wave][0][c][48 + quad * 4] = oa3;
    *(f32x4*)&obuf[wave][1][c][ 0 + quad * 4] = ob0;
    *(f32x4*)&obuf[wave][1][c][16 + quad * 4] = ob1;
    *(f32x4*)&obuf[wave][1][c][32 + quad * 4] = ob2;
    *(f32x4*)&obuf[wave][1][c][48 + quad * 4] = ob3;
    if (quad == 0) { lbuf[wave][0][c] = lA; lbuf[wave][1][c] = lB; }
    __syncthreads();

    // ---- combine 4 key-range partials; 256 thr x 8 floats, coalesced ----
    const int tid = threadIdx.x;
    const int row = tid >> 3;                    // block-local q row (0..31)
    const int d0  = (tid & 7) * 8;               // d base (0..56)
    const int qt  = row >> 4;
    const int r   = row & 15;
    const float L = (lbuf[0][qt][r] + lbuf[1][qt][r]) +
                    (lbuf[2][qt][r] + lbuf[3][qt][r]);
    const float rl = 1.f / L;
    f32x4 Oa = {0,0,0,0}, Ob = {0,0,0,0};
    #pragma unroll
    for (int w = 0; w < 4; w++) {
        f32x4 a = *(const f32x4*)&obuf[w][qt][r][d0];
        f32x4 bfr = *(const f32x4*)&obuf[w][qt][r][d0 + 4];
        Oa[0] += a[0]; Oa[1] += a[1]; Oa[2] += a[2]; Oa[3] += a[3];
        Ob[0] += bfr[0]; Ob[1] += bfr[1]; Ob[2] += bfr[2]; Ob[3] += bfr[3];
    }
    Oa[0] *= rl; Oa[1] *= rl; Oa[2] *= rl; Oa[3] *= rl;
    Ob[0] *= rl; Ob[1] *= rl; Ob[2] *= rl; Ob[3] *= rl;
    float* op = out + (size_t)(tb + row) * 64 + d0;
    *(f32x4*)op       = Oa;
    *(f32x4*)(op + 4) = Ob;
}

// ---------------------------------------------------------------------------
extern "C" void kernel_launch(void* const* d_in, const int* in_sizes, int n_in,
                              void* d_out, int out_size, void* d_ws, size_t ws_size,
                              hipStream_t stream)
{
    const float* x  = (const float*)d_in[0];
    const float* Wk = (const float*)d_in[1];
    const float* Wq = (const float*)d_in[2];
    const float* Wv = (const float*)d_in[3];
    float* out = (float*)d_out;

    char* ws = (char*)d_ws;
    unsigned short* qg  = (unsigned short*)(ws);                  // 2 MiB
    unsigned short* kg2 = (unsigned short*)(ws + (2u << 20));     // 2 MiB
    unsigned short* vg2 = (unsigned short*)(ws + (4u << 20));     // 2 MiB
    unsigned short* wt2 = (unsigned short*)(ws + (6u << 20));     // 192 KiB
    unsigned short* xb2 = (unsigned short*)(ws + (7u << 20));     // 16 MiB

    hipLaunchKernelGGL(prep_kernel, dim3(4144), dim3(256), 0, stream,
                       x, Wq, Wk, Wv, xb2, wt2);
    hipLaunchKernelGGL(proj_kernel, dim3(768),  dim3(256), 0, stream,
                       xb2, wt2, qg, kg2, vg2);
    hipLaunchKernelGGL(attn_kernel, dim3(512),  dim3(256), 0, stream,
                       qg, kg2, vg2, out);
}